// Round 1
// baseline (46.293 us; speedup 1.0000x reference)
//
#include <hip/hip_runtime.h>

// SoftPattern: score = sum_{t=4}^{T-1} prod_{j=0}^{4} sigmoid(e_{doc[t-j]} . W[:,4-j] + b[4-j])
// where W = diags[1] (only forward diagonal used), only pattern positions 0..4 matter.
//
// Plan:
//  K1: per-vocab projection+sigmoid table sig[v][p], p=0..4 (stride-8 rows for alignment)
//  K2: per-window 5-term product, block partial sums (deterministic)
//  K3: final reduction of partials -> d_out[0]

#define WORD_DIM 300
#define VOCAB    50000
#define PLEN     6
#define DOC_LEN  500000

#define K1_BLOCK 256
#define K2_BLOCK 256

// ---------------- Kernel 1: sig[v][p] = sigmoid(sum_d E[d][v]*W[d][p] + b[p]) ----------------
__global__ __launch_bounds__(K1_BLOCK) void proj_sig_kernel(
    const float* __restrict__ emb,    // (WORD_DIM, VOCAB) row-major
    const float* __restrict__ diags,  // (3, WORD_DIM, PLEN)
    const float* __restrict__ bias,   // (3, PLEN)
    float* __restrict__ sig)          // (VOCAB, 8) rows, cols 0..4 valid
{
    __shared__ float wl[WORD_DIM * 5];
    __shared__ float bl[5];
    const int tid = threadIdx.x;
    // stage W = diags[1][d][p], p=0..4 into LDS with stride 5
    for (int i = tid; i < WORD_DIM * 5; i += K1_BLOCK) {
        int d = i / 5;
        int p = i - d * 5;
        wl[i] = diags[WORD_DIM * PLEN + d * PLEN + p];
    }
    if (tid < 5) bl[tid] = bias[PLEN + tid];
    __syncthreads();

    const int v = blockIdx.x * K1_BLOCK + tid;
    if (v >= VOCAB) return;

    float a0 = 0.f, a1 = 0.f, a2 = 0.f, a3 = 0.f, a4 = 0.f;
    const float* __restrict__ col = emb + v;
    #pragma unroll 4
    for (int d = 0; d < WORD_DIM; ++d) {
        float x = col[(size_t)d * VOCAB];       // coalesced across threads (consecutive v)
        const float* w = &wl[d * 5];            // wave-uniform address -> LDS broadcast
        a0 += x * w[0];
        a1 += x * w[1];
        a2 += x * w[2];
        a3 += x * w[3];
        a4 += x * w[4];
    }
    float* row = sig + (size_t)v * 8;
    row[0] = 1.f / (1.f + __expf(-(a0 + bl[0])));
    row[1] = 1.f / (1.f + __expf(-(a1 + bl[1])));
    row[2] = 1.f / (1.f + __expf(-(a2 + bl[2])));
    row[3] = 1.f / (1.f + __expf(-(a3 + bl[3])));
    row[4] = 1.f / (1.f + __expf(-(a4 + bl[4])));
}

// ---------------- Kernel 2: windowed products + block partial sums ----------------
__global__ __launch_bounds__(K2_BLOCK) void score_kernel(
    const int* __restrict__ doc,      // (DOC_LEN,)
    const float* __restrict__ sig,    // (VOCAB, 8)
    float* __restrict__ partials)     // (gridDim.x,)
{
    const int t = blockIdx.x * K2_BLOCK + threadIdx.x + 4;  // window end position
    float prod = 0.f;
    if (t < DOC_LEN) {
        prod = sig[(size_t)doc[t    ] * 8 + 4]
             * sig[(size_t)doc[t - 1] * 8 + 3]
             * sig[(size_t)doc[t - 2] * 8 + 2]
             * sig[(size_t)doc[t - 3] * 8 + 1]
             * sig[(size_t)doc[t - 4] * 8 + 0];
    }
    // wave (64-lane) reduction
    #pragma unroll
    for (int off = 32; off > 0; off >>= 1)
        prod += __shfl_down(prod, off, 64);
    __shared__ float wsum[K2_BLOCK / 64];
    const int lane = threadIdx.x & 63;
    const int wid  = threadIdx.x >> 6;
    if (lane == 0) wsum[wid] = prod;
    __syncthreads();
    if (threadIdx.x == 0) {
        float s = 0.f;
        #pragma unroll
        for (int w = 0; w < K2_BLOCK / 64; ++w) s += wsum[w];
        partials[blockIdx.x] = s;
    }
}

// ---------------- Kernel 3: final deterministic reduction ----------------
__global__ __launch_bounds__(256) void reduce_kernel(
    const float* __restrict__ partials, int n, float* __restrict__ out)
{
    float s = 0.f;
    for (int i = threadIdx.x; i < n; i += 256) s += partials[i];
    #pragma unroll
    for (int off = 32; off > 0; off >>= 1)
        s += __shfl_down(s, off, 64);
    __shared__ float wsum[4];
    const int lane = threadIdx.x & 63;
    const int wid  = threadIdx.x >> 6;
    if (lane == 0) wsum[wid] = s;
    __syncthreads();
    if (threadIdx.x == 0) out[0] = wsum[0] + wsum[1] + wsum[2] + wsum[3];
}

extern "C" void kernel_launch(void* const* d_in, const int* in_sizes, int n_in,
                              void* d_out, int out_size, void* d_ws, size_t ws_size,
                              hipStream_t stream) {
    const float* emb   = (const float*)d_in[0];   // (300, 50000)
    const float* diags = (const float*)d_in[1];   // (3, 300, 6)
    const float* bias  = (const float*)d_in[2];   // (3, 6)
    const int*   doc   = (const int*)d_in[3];     // (500000,)
    float* out = (float*)d_out;

    float* ws = (float*)d_ws;
    float* sig      = ws;                 // VOCAB*8 floats = 1.6 MB
    float* partials = ws + VOCAB * 8;     // block partial sums

    const int blocks1 = (VOCAB + K1_BLOCK - 1) / K1_BLOCK;           // 196
    const int nwin    = DOC_LEN - 4;                                 // 499996
    const int blocks2 = (nwin + K2_BLOCK - 1) / K2_BLOCK;            // 1954

    proj_sig_kernel<<<blocks1, K1_BLOCK, 0, stream>>>(emb, diags, bias, sig);
    score_kernel<<<blocks2, K2_BLOCK, 0, stream>>>(doc, sig, partials);
    reduce_kernel<<<1, 256, 0, stream>>>(partials, blocks2, out);
}

// Round 2
// 29.942 us; speedup vs baseline: 1.5461x; 1.5461x over previous
//
#include <hip/hip_runtime.h>

// SoftPattern: score = sum_{t=4}^{T-1} prod_{p=0}^{4} sigmoid(e_{doc[t-4+p]} . W[:,p] + b[p])
// W = diags[1]; only pattern positions 0..4 contribute (hidden[5] tap fed by gate[0..4] chain).
//
// K1a: D-split partial projection  partial[p][c][v] (10 chunks of 30 rows) - saturates HBM
// K1b: combine + bias + sigmoid -> sig[v][8]
// K2 : windowed 5-term products, LDS-staged token rows, block partial sums
// K3 : final deterministic reduction

#define WORD_DIM 300
#define VOCAB    50000
#define PLEN     6
#define DOC_LEN  500000

#define DSPLIT 10
#define DCHUNK 30      // WORD_DIM / DSPLIT

// ------------- K1a: partial[p][c][v2..v2+1] = sum_{d in chunk c} E[d][v]*W[d][p] -------------
__global__ __launch_bounds__(256) void proj_partial_kernel(
    const float* __restrict__ emb,     // (WORD_DIM, VOCAB)
    const float* __restrict__ diags,   // (3, WORD_DIM, PLEN)
    float* __restrict__ partial)       // (5, DSPLIT, VOCAB)
{
    __shared__ float wl[DCHUNK * 5];
    const int tid = threadIdx.x;
    const int c   = blockIdx.y;
    const int d0  = c * DCHUNK;
    for (int i = tid; i < DCHUNK * 5; i += 256) {
        int d = d0 + i / 5, p = i % 5;
        wl[i] = diags[WORD_DIM * PLEN + d * PLEN + p];   // diags[1][d][p]
    }
    __syncthreads();

    const int v2 = (blockIdx.x * 256 + tid) * 2;
    if (v2 >= VOCAB) return;

    float ax[5] = {0.f, 0.f, 0.f, 0.f, 0.f};
    float ay[5] = {0.f, 0.f, 0.f, 0.f, 0.f};
    #pragma unroll
    for (int dd = 0; dd < DCHUNK; ++dd) {
        float2 x = *reinterpret_cast<const float2*>(&emb[(size_t)(d0 + dd) * VOCAB + v2]);
        #pragma unroll
        for (int p = 0; p < 5; ++p) {
            float w = wl[dd * 5 + p];
            ax[p] += x.x * w;
            ay[p] += x.y * w;
        }
    }
    #pragma unroll
    for (int p = 0; p < 5; ++p) {
        float2 o; o.x = ax[p]; o.y = ay[p];
        *reinterpret_cast<float2*>(&partial[(size_t)(p * DSPLIT + c) * VOCAB + v2]) = o;
    }
}

// ------------- K1b: sig[v][p] = sigmoid(sum_c partial[p][c][v] + b[p]) -------------
__global__ __launch_bounds__(256) void combine_sig_kernel(
    const float* __restrict__ partial,
    const float* __restrict__ bias,    // (3, PLEN)
    float* __restrict__ sig)           // (VOCAB, 8)
{
    const int v = blockIdx.x * 256 + threadIdx.x;
    if (v >= VOCAB) return;
    #pragma unroll
    for (int p = 0; p < 5; ++p) {
        float s = bias[PLEN + p];      // bias[1][p], wave-uniform
        #pragma unroll
        for (int c = 0; c < DSPLIT; ++c)
            s += partial[(size_t)(p * DSPLIT + c) * VOCAB + v];
        sig[(size_t)v * 8 + p] = 1.f / (1.f + __expf(-s));
    }
}

// ------------- K2: windowed products, LDS-staged rows -------------
#define K2_BLOCK 256
#define K2_TOK   (K2_BLOCK + 4)

__global__ __launch_bounds__(K2_BLOCK) void score_kernel(
    const int* __restrict__ doc,
    const float* __restrict__ sig,     // (VOCAB, 8)
    float* __restrict__ partials)
{
    __shared__ float srow[5][K2_TOK];  // plane-per-position: conflict-free stride-1 access
    const int tid  = threadIdx.x;
    const int base = blockIdx.x * K2_BLOCK + 4;      // first window end t of this block
    for (int i = tid; i < K2_TOK; i += K2_BLOCK) {
        int tok_t = base - 4 + i;
        if (tok_t < DOC_LEN) {
            const float* row = &sig[(size_t)doc[tok_t] * 8];
            float4 r4 = *reinterpret_cast<const float4*>(row);
            srow[0][i] = r4.x; srow[1][i] = r4.y; srow[2][i] = r4.z; srow[3][i] = r4.w;
            srow[4][i] = row[4];
        }
    }
    __syncthreads();

    const int t = base + tid;
    float prod = 0.f;
    if (t < DOC_LEN) {
        // window t: prod_p sig[doc[t-4+p]][p]; local token idx = tid + p
        prod = srow[0][tid] * srow[1][tid + 1] * srow[2][tid + 2]
             * srow[3][tid + 3] * srow[4][tid + 4];
    }
    #pragma unroll
    for (int off = 32; off > 0; off >>= 1)
        prod += __shfl_down(prod, off, 64);
    __shared__ float wsum[K2_BLOCK / 64];
    const int lane = tid & 63;
    const int wid  = tid >> 6;
    if (lane == 0) wsum[wid] = prod;
    __syncthreads();
    if (tid == 0) {
        float s = 0.f;
        #pragma unroll
        for (int w = 0; w < K2_BLOCK / 64; ++w) s += wsum[w];
        partials[blockIdx.x] = s;
    }
}

// ------------- K3: final reduction -------------
__global__ __launch_bounds__(256) void reduce_kernel(
    const float* __restrict__ partials, int n, float* __restrict__ out)
{
    float s = 0.f;
    for (int i = threadIdx.x; i < n; i += 256) s += partials[i];
    #pragma unroll
    for (int off = 32; off > 0; off >>= 1)
        s += __shfl_down(s, off, 64);
    __shared__ float wsum[4];
    const int lane = threadIdx.x & 63;
    const int wid  = threadIdx.x >> 6;
    if (lane == 0) wsum[wid] = s;
    __syncthreads();
    if (threadIdx.x == 0) out[0] = wsum[0] + wsum[1] + wsum[2] + wsum[3];
}

extern "C" void kernel_launch(void* const* d_in, const int* in_sizes, int n_in,
                              void* d_out, int out_size, void* d_ws, size_t ws_size,
                              hipStream_t stream) {
    const float* emb   = (const float*)d_in[0];   // (300, 50000)
    const float* diags = (const float*)d_in[1];   // (3, 300, 6)
    const float* bias  = (const float*)d_in[2];   // (3, 6)
    const int*   doc   = (const int*)d_in[3];     // (500000,)
    float* out = (float*)d_out;

    float* ws = (float*)d_ws;
    float* sig     = ws;                          // VOCAB*8        = 400000 f (1.6 MB)
    float* partial = sig + (size_t)VOCAB * 8;     // 5*DSPLIT*VOCAB = 2.5M f (10 MB)
    float* bpart   = partial + (size_t)5 * DSPLIT * VOCAB;  // block partials

    const int blocks1 = (VOCAB / 2 + 255) / 256;             // 98
    const int blocksC = (VOCAB + 255) / 256;                 // 196
    const int nwin    = DOC_LEN - 4;                         // 499996
    const int blocks2 = (nwin + K2_BLOCK - 1) / K2_BLOCK;    // 1954

    dim3 g1(blocks1, DSPLIT);
    proj_partial_kernel<<<g1, 256, 0, stream>>>(emb, diags, partial);
    combine_sig_kernel<<<blocksC, 256, 0, stream>>>(partial, bias, sig);
    score_kernel<<<blocks2, K2_BLOCK, 0, stream>>>(doc, sig, bpart);
    reduce_kernel<<<1, 256, 0, stream>>>(bpart, blocks2, out);
}

// Round 3
// 26.047 us; speedup vs baseline: 1.7773x; 1.1496x over previous
//
#include <hip/hip_runtime.h>

// SoftPattern: score = sum_{t=4}^{T-1} prod_{p=0}^{4} sigmoid(e_{doc[t-4+p]} . W[:,p] + b[p])
// W = diags[1]; only pattern positions 0..4 contribute.
//
// K1: fused projection+combine+sigmoid -> sig[v][8]
//     768-thread blocks: 6 d-groups x 128 threads; group-local partial dot
//     products combined through LDS (no global partial round-trip).
// K2: windowed 5-term products, LDS-staged token rows, 1024-thread blocks
// K3: final deterministic reduction

#define WORD_DIM 300
#define VOCAB    50000
#define PLEN     6
#define DOC_LEN  500000

#define GROUPS   6
#define GSIZE    128
#define DCHUNK   50                    // WORD_DIM / GROUPS
#define K1_BLOCK (GROUPS * GSIZE)      // 768

// ------------- K1: sig[v][p] = sigmoid(sum_d E[d][v]*W[d][p] + b[p]) -------------
__global__ __launch_bounds__(K1_BLOCK) void proj_sig_fused(
    const float* __restrict__ emb,     // (WORD_DIM, VOCAB)
    const float* __restrict__ diags,   // (3, WORD_DIM, PLEN)
    const float* __restrict__ bias,    // (3, PLEN)
    float* __restrict__ sig)           // (VOCAB, 8) rows, cols 0..4 valid
{
    __shared__ float wl[WORD_DIM * 5];                   // 6 KB
    __shared__ float part[GROUPS - 1][GSIZE][10];        // 25.6 KB
    const int tid = threadIdx.x;
    for (int i = tid; i < WORD_DIM * 5; i += K1_BLOCK) {
        int d = i / 5, p = i % 5;
        wl[i] = diags[WORD_DIM * PLEN + d * PLEN + p];   // diags[1][d][p]
    }
    __syncthreads();

    const int g  = tid / GSIZE;        // d-group
    const int u  = tid % GSIZE;        // vocab-pair lane (wave-aligned: coalesced)
    const int v2 = blockIdx.x * (2 * GSIZE) + u * 2;
    const int d0 = g * DCHUNK;

    float a[10] = {0.f, 0.f, 0.f, 0.f, 0.f, 0.f, 0.f, 0.f, 0.f, 0.f};
    if (v2 < VOCAB) {
        const float* __restrict__ col = emb + (size_t)d0 * VOCAB + v2;
        #pragma unroll 10
        for (int dd = 0; dd < DCHUNK; ++dd) {
            float2 x = *reinterpret_cast<const float2*>(&col[(size_t)dd * VOCAB]);
            const float* w = &wl[(d0 + dd) * 5];         // wave-uniform -> LDS broadcast
            a[0] += x.x * w[0]; a[1] += x.x * w[1]; a[2] += x.x * w[2];
            a[3] += x.x * w[3]; a[4] += x.x * w[4];
            a[5] += x.y * w[0]; a[6] += x.y * w[1]; a[7] += x.y * w[2];
            a[8] += x.y * w[3]; a[9] += x.y * w[4];
        }
    }
    if (g > 0) {
        #pragma unroll
        for (int k = 0; k < 10; ++k) part[g - 1][u][k] = a[k];
    }
    __syncthreads();
    if (g == 0 && v2 < VOCAB) {
        #pragma unroll
        for (int k = 0; k < 10; ++k) {
            float s = a[k];
            #pragma unroll
            for (int q = 0; q < GROUPS - 1; ++q) s += part[q][u][k];
            a[k] = s;
        }
        float* r0 = &sig[(size_t)v2 * 8];
        float* r1 = &sig[(size_t)(v2 + 1) * 8];
        #pragma unroll
        for (int p = 0; p < 5; ++p) {
            float b = bias[PLEN + p];                    // bias[1][p]
            r0[p] = 1.f / (1.f + __expf(-(a[p]     + b)));
            r1[p] = 1.f / (1.f + __expf(-(a[5 + p] + b)));
        }
    }
}

// ------------- K2: windowed products, LDS-staged rows -------------
#define K2_BLOCK 1024
#define K2_TOK   (K2_BLOCK + 4)

__global__ __launch_bounds__(K2_BLOCK) void score_kernel(
    const int* __restrict__ doc,
    const float* __restrict__ sig,     // (VOCAB, 8)
    float* __restrict__ partials)
{
    __shared__ float srow[5][K2_TOK];  // plane-per-position: conflict-free stride-1
    const int tid  = threadIdx.x;
    const int base = blockIdx.x * K2_BLOCK + 4;          // first window end t
    for (int i = tid; i < K2_TOK; i += K2_BLOCK) {
        int tok_t = base - 4 + i;
        if (tok_t < DOC_LEN) {
            const float* row = &sig[(size_t)doc[tok_t] * 8];
            float4 r4 = *reinterpret_cast<const float4*>(row);
            srow[0][i] = r4.x; srow[1][i] = r4.y; srow[2][i] = r4.z; srow[3][i] = r4.w;
            srow[4][i] = row[4];
        }
    }
    __syncthreads();

    const int t = base + tid;
    float prod = 0.f;
    if (t < DOC_LEN) {
        prod = srow[0][tid] * srow[1][tid + 1] * srow[2][tid + 2]
             * srow[3][tid + 3] * srow[4][tid + 4];
    }
    #pragma unroll
    for (int off = 32; off > 0; off >>= 1)
        prod += __shfl_down(prod, off, 64);
    __shared__ float wsum[K2_BLOCK / 64];
    const int lane = tid & 63;
    const int wid  = tid >> 6;
    if (lane == 0) wsum[wid] = prod;
    __syncthreads();
    if (tid == 0) {
        float s = 0.f;
        #pragma unroll
        for (int w = 0; w < K2_BLOCK / 64; ++w) s += wsum[w];
        partials[blockIdx.x] = s;
    }
}

// ------------- K3: final reduction -------------
__global__ __launch_bounds__(512) void reduce_kernel(
    const float* __restrict__ partials, int n, float* __restrict__ out)
{
    float s = 0.f;
    for (int i = threadIdx.x; i < n; i += 512) s += partials[i];
    #pragma unroll
    for (int off = 32; off > 0; off >>= 1)
        s += __shfl_down(s, off, 64);
    __shared__ float wsum[8];
    const int lane = threadIdx.x & 63;
    const int wid  = threadIdx.x >> 6;
    if (lane == 0) wsum[wid] = s;
    __syncthreads();
    if (threadIdx.x == 0) {
        float t = 0.f;
        #pragma unroll
        for (int w = 0; w < 8; ++w) t += wsum[w];
        out[0] = t;
    }
}

extern "C" void kernel_launch(void* const* d_in, const int* in_sizes, int n_in,
                              void* d_out, int out_size, void* d_ws, size_t ws_size,
                              hipStream_t stream) {
    const float* emb   = (const float*)d_in[0];   // (300, 50000)
    const float* diags = (const float*)d_in[1];   // (3, 300, 6)
    const float* bias  = (const float*)d_in[2];   // (3, 6)
    const int*   doc   = (const int*)d_in[3];     // (500000,)
    float* out = (float*)d_out;

    float* ws = (float*)d_ws;
    float* sig   = ws;                            // VOCAB*8 floats = 1.6 MB
    float* bpart = sig + (size_t)VOCAB * 8;       // block partials

    const int blocks1 = (VOCAB + 2 * GSIZE - 1) / (2 * GSIZE);       // 196
    const int nwin    = DOC_LEN - 4;                                 // 499996
    const int blocks2 = (nwin + K2_BLOCK - 1) / K2_BLOCK;            // 489

    proj_sig_fused<<<blocks1, K1_BLOCK, 0, stream>>>(emb, diags, bias, sig);
    score_kernel<<<blocks2, K2_BLOCK, 0, stream>>>(doc, sig, bpart);
    reduce_kernel<<<1, 512, 0, stream>>>(bpart, blocks2, out);
}